// Round 6
// baseline (205.261 us; speedup 1.0000x reference)
//
#include <hip/hip_runtime.h>
#include <stdint.h>
#include <float.h>

#define BLK 256
#define IPT 4                   // owner points per thread
#define OWNERS (BLK * IPT)      // 1024 owners per block / per chunk
#define SLICE 256               // candidates per stage (4 KB LDS SoA)
#define NSTAGE 2                // stages per block -> CPB candidates scanned
#define CPB (SLICE * NSTAGE)    // 512 candidates per block
#define SUB 64                  // subtile granularity for deferred-index recovery

typedef unsigned long long ull;
typedef unsigned int u32;
typedef float v2f __attribute__((ext_vector_type(2)));

__device__ __forceinline__ v2f fma2(v2f a, v2f b, v2f c) {
    return __builtin_elementwise_fma(a, b, c);   // -> v_pk_fma_f32 (IEEE fma/half)
}

// Monotone float -> uint transform (preserves <, total order) and inverse.
__device__ __forceinline__ unsigned int ford(float f) {
    int b = __float_as_int(f);
    return (b >= 0) ? ((unsigned)b ^ 0x80000000u) : ~(unsigned)b;
}
__device__ __forceinline__ float ford_inv(unsigned int u) {
    int b = (u & 0x80000000u) ? (int)(u ^ 0x80000000u) : (int)~u;
    return __int_as_float(b);
}

// Single fused dispatch (plus one 330 KB memset):
//  - phase 1: r5's verified pk_fma hot loop, but IPT=4 and TWO sequential
//    256-pt stages per block => 512 cands/block => 1.05M atomicMins (4x fewer
//    than r5's 4.19M; theory: the u64-atomic coherence-point stream is the
//    ~46 us floor).
//  - last block per chunk finalizes in-dispatch (r4-VERIFIED bit-exact flow).
//    FENCE-FREE (r2/r4 lesson: per-block __threadfence = L2 wbinv = 6x slowdown):
//    ordering via per-wave `s_waitcnt vmcnt(0)` (atomics complete at coherence
//    before counter bump); visibility via agent-scope ATOMIC loads of
//    ATOMICALLY-written locations. No spin-waits => no deadlock possible.
__global__ __launch_bounds__(BLK) void nn_fused(
    const float* __restrict__ p, const float* __restrict__ g,
    const float* __restrict__ pn, const float* __restrict__ gn,
    ull* __restrict__ mins, u32* __restrict__ ctr, u32* __restrict__ done,
    float* __restrict__ csum, float* __restrict__ out, int N, int M)
{
    __shared__ float sbx[SLICE], sby[SLICE], sbz[SLICE], sbw[SLICE];
    __shared__ u32 lastFlag;
    __shared__ float partial[BLK / 64];

    const int rowChunks = N / OWNERS;              // 8
    const int colChunks = M / OWNERS;              // 32
    const int rowGroups = M / CPB;                 // 64
    const int colGroups = N / CPB;                 // 16
    const int rowBlocks = rowChunks * rowGroups;   // 512
    const int nChunks = rowChunks + colChunks;     // 40

    const float* A; const float* B; const float* An; const float* Bn;
    ull* minsSide; int id, nGroups; float inv;
    const bool rowSide = (int)blockIdx.x < rowBlocks;
    if (rowSide) {
        id = blockIdx.x;             A = p; B = g; An = pn; Bn = gn;
        minsSide = mins;     nGroups = rowGroups; inv = 1.0f / (float)N;
    } else {
        id = blockIdx.x - rowBlocks; A = g; B = p; An = gn; Bn = pn;
        minsSide = mins + N; nGroups = colGroups; inv = 1.0f / (float)M;
    }
    const int chunk = id / nGroups;
    const int group = id - chunk * nGroups;
    const int chunkG = rowSide ? chunk : (rowChunks + chunk);

    // ---- owner prologue (registers persist across stages) ----
    const int o0 = chunk * OWNERS + threadIdx.x;
    v2f ax2[IPT], ay2[IPT], az2[IPT];
    float best[IPT];
    int base[IPT];
#pragma unroll
    for (int r = 0; r < IPT; ++r) {
        int o = o0 + r * BLK;
        float axv = -2.0f * A[3 * o];
        float ayv = -2.0f * A[3 * o + 1];
        float azv = -2.0f * A[3 * o + 2];
        ax2[r] = (v2f){axv, axv};
        ay2[r] = (v2f){ayv, ayv};
        az2[r] = (v2f){azv, azv};
        best[r] = FLT_MAX;
        base[r] = group * CPB;
    }

    // ---- phase 1: NSTAGE sequential slices, ascending s ----
    for (int stage = 0; stage < NSTAGE; ++stage) {
        const int gs0 = group * CPB + stage * SLICE;
        if (stage) __syncthreads();        // readers of previous stage done

        // Stage slice SoA (coords + |B|^2). Explicit fmaf: finalize recomputes
        // the identical expression so bit-exact equality holds.
        {
            int s = gs0 + threadIdx.x;     // SLICE == BLK: one candidate/thread
            float bx = B[3 * s], by = B[3 * s + 1], bz = B[3 * s + 2];
            float w = fmaf(bz, bz, fmaf(by, by, bx * bx));
            sbx[threadIdx.x] = bx; sby[threadIdx.x] = by;
            sbz[threadIdx.x] = bz; sbw[threadIdx.x] = w;
        }
        __syncthreads();

        for (int st = 0; st < SLICE; st += SUB) {
            float prev[IPT];
#pragma unroll
            for (int r = 0; r < IPT; ++r) prev[r] = best[r];
#pragma unroll 2
            for (int k = st; k < st + SUB; k += 2) {
                v2f qx = *(const v2f*)&sbx[k];   // k even -> 8B aligned broadcast
                v2f qy = *(const v2f*)&sby[k];
                v2f qz = *(const v2f*)&sbz[k];
                v2f qw = *(const v2f*)&sbw[k];
#pragma unroll
                for (int r = 0; r < IPT; ++r) {
                    v2f t = fma2(az2[r], qz, qw);     // 3 pk_fma = 2 candidates
                    t = fma2(ay2[r], qy, t);
                    t = fma2(ax2[r], qx, t);
                    best[r] = fminf(fminf(t.x, t.y), best[r]);   // -> v_min3_f32
                }
            }
#pragma unroll
            for (int r = 0; r < IPT; ++r)
                if (best[r] < prev[r]) base[r] = gs0 + st;  // strict <: first wins
        }
    }

#pragma unroll
    for (int r = 0; r < IPT; ++r) {
        ull packed = ((ull)ford(best[r]) << 32) | (unsigned)base[r];
        atomicMin(&minsSide[o0 + r * BLK], packed);   // device-scope RMW
    }

    // ---- last-block detection (fence-free release) ----
    asm volatile("s_waitcnt vmcnt(0)" ::: "memory");  // my atomics at coherence
    __syncthreads();                                  // all threads drained
    if (threadIdx.x == 0) {
        u32 old = atomicAdd(&ctr[chunkG], 1u);        // ctr init = 0xFFFFFFFF
        lastFlag = (old == (u32)(nGroups - 2)) ? 1u : 0u;
    }
    __syncthreads();
    if (!lastFlag) return;

    // ---- in-dispatch finalize of this chunk (r4-verified bit-exact flow) ----
    float c = 0.0f;
#pragma unroll
    for (int r = 0; r < IPT; ++r) {
        int o = chunk * OWNERS + threadIdx.x + r * BLK;
        // agent-scope atomic load: reads the coherence point (no cache flush)
        ull packed = __hip_atomic_load(&minsSide[o], __ATOMIC_RELAXED,
                                       __HIP_MEMORY_SCOPE_AGENT);
        float axx = -2.0f * A[3 * o];
        float ayy = -2.0f * A[3 * o + 1];
        float azz = -2.0f * A[3 * o + 2];
        float bestf = ford_inv((unsigned int)(packed >> 32));
        int b0 = (int)(packed & 0xffffffffull);

        // Branchless bit-exact first-match rescan (verified absmax=0 path).
        int idx = 0x7fffffff;
#pragma unroll 4
        for (int jj = 0; jj < SUB; ++jj) {
            int s = b0 + jj;
            float bx = B[3 * s], by = B[3 * s + 1], bz = B[3 * s + 2];
            float w = fmaf(bz, bz, fmaf(by, by, bx * bx));
            float v = fmaf(axx, bx, fmaf(ayy, by, fmaf(azz, bz, w)));
            int cand = (v == bestf) ? s : 0x7fffffff;
            idx = (cand < idx) ? cand : idx;     // ascending -> first match
        }
        if (idx == 0x7fffffff) idx = b0;         // defensive; cannot trigger

        float d = An[3 * o] * Bn[3 * idx] + An[3 * o + 1] * Bn[3 * idx + 1]
                + An[3 * o + 2] * Bn[3 * idx + 2];
        c += (1.0f - d) * inv;
    }

#pragma unroll
    for (int off = 32; off > 0; off >>= 1) c += __shfl_down(c, off, 64);
    if ((threadIdx.x & 63) == 0) partial[threadIdx.x >> 6] = c;
    __syncthreads();
    if (threadIdx.x == 0) {
        float s = 0.0f;
#pragma unroll
        for (int w = 0; w < BLK / 64; ++w) s += partial[w];
        atomicExch(&csum[chunkG], s);                      // coherent RMW store
        asm volatile("s_waitcnt vmcnt(0)" ::: "memory");   // csum at coherence
        u32 od = atomicAdd(done, 1u);                      // done init = -1
        if (od == (u32)(nChunks - 2)) {                    // globally last
            float tot = 0.0f;
            for (int k2 = 0; k2 < nChunks; ++k2)
                tot += __hip_atomic_load(&csum[k2], __ATOMIC_RELAXED,
                                         __HIP_MEMORY_SCOPE_AGENT);
            *out = tot;                      // end-of-kernel flush -> host
        }
    }
}

// ======================= legacy fallback (r5-verified 3-dispatch path) =======================
#define L_IPT 8
#define L_OWNERS (BLK * L_IPT)
#define L_SLICE 128
#define FBLK 64

__global__ __launch_bounds__(BLK) void nn_min_dual(
    const float* __restrict__ p, const float* __restrict__ g,
    ull* __restrict__ rowmin, ull* __restrict__ colmin,
    float* __restrict__ out, int rowBlocks, int rowSlices, int colSlices)
{
    __shared__ float sbx[L_SLICE], sby[L_SLICE], sbz[L_SLICE], sbw[L_SLICE];
    if (blockIdx.x == 0 && threadIdx.x == 0) *out = 0.0f;
    const float* A; const float* B; ull* outmin; int id, nSlices;
    if ((int)blockIdx.x < rowBlocks) {
        id = blockIdx.x;             A = p; B = g; outmin = rowmin; nSlices = rowSlices;
    } else {
        id = blockIdx.x - rowBlocks; A = g; B = p; outmin = colmin; nSlices = colSlices;
    }
    const int chunk = id / nSlices;
    const int slice = id - chunk * nSlices;
    const int s0 = slice * L_SLICE;
    if (threadIdx.x < L_SLICE) {
        int s = s0 + threadIdx.x;
        float bx = B[3 * s], by = B[3 * s + 1], bz = B[3 * s + 2];
        float w = fmaf(bz, bz, fmaf(by, by, bx * bx));
        sbx[threadIdx.x] = bx; sby[threadIdx.x] = by;
        sbz[threadIdx.x] = bz; sbw[threadIdx.x] = w;
    }
    const int o0 = chunk * L_OWNERS + threadIdx.x;
    v2f ax2[L_IPT], ay2[L_IPT], az2[L_IPT];
    float best[L_IPT]; int base[L_IPT];
#pragma unroll
    for (int r = 0; r < L_IPT; ++r) {
        int o = o0 + r * BLK;
        float axv = -2.0f * A[3 * o], ayv = -2.0f * A[3 * o + 1], azv = -2.0f * A[3 * o + 2];
        ax2[r] = (v2f){axv, axv}; ay2[r] = (v2f){ayv, ayv}; az2[r] = (v2f){azv, azv};
        best[r] = FLT_MAX; base[r] = s0;
    }
    __syncthreads();
    for (int st = 0; st < L_SLICE; st += SUB) {
        float prev[L_IPT];
#pragma unroll
        for (int r = 0; r < L_IPT; ++r) prev[r] = best[r];
#pragma unroll 2
        for (int k = st; k < st + SUB; k += 2) {
            v2f qx = *(const v2f*)&sbx[k]; v2f qy = *(const v2f*)&sby[k];
            v2f qz = *(const v2f*)&sbz[k]; v2f qw = *(const v2f*)&sbw[k];
#pragma unroll
            for (int r = 0; r < L_IPT; ++r) {
                v2f t = fma2(az2[r], qz, qw);
                t = fma2(ay2[r], qy, t);
                t = fma2(ax2[r], qx, t);
                best[r] = fminf(fminf(t.x, t.y), best[r]);
            }
        }
#pragma unroll
        for (int r = 0; r < L_IPT; ++r)
            if (best[r] < prev[r]) base[r] = s0 + st;
    }
#pragma unroll
    for (int r = 0; r < L_IPT; ++r) {
        ull packed = ((ull)ford(best[r]) << 32) | (unsigned)base[r];
        atomicMin(&outmin[o0 + r * BLK], packed);
    }
}

__global__ __launch_bounds__(FBLK) void finalize_kernel(
    const ull* __restrict__ rowmin, const ull* __restrict__ colmin,
    const float* __restrict__ p, const float* __restrict__ g,
    const float* __restrict__ pn, const float* __restrict__ gn,
    float* __restrict__ out, int N, int M, float invN, float invM)
{
    int t = blockIdx.x * FBLK + threadIdx.x;
    float c = 0.0f;
    if (t < N + M) {
        const float* A; const float* B; const float* An; const float* Bn;
        ull packed; int o; float inv;
        if (t < N) { o = t;     A = p; B = g; An = pn; Bn = gn; packed = rowmin[o]; inv = invN; }
        else       { o = t - N; A = g; B = p; An = gn; Bn = pn; packed = colmin[o]; inv = invM; }
        float ax = -2.0f * A[3 * o], ay = -2.0f * A[3 * o + 1], az = -2.0f * A[3 * o + 2];
        float bestf = ford_inv((unsigned int)(packed >> 32));
        int b0 = (int)(packed & 0xffffffffull);
        int idx = 0x7fffffff;
#pragma unroll 4
        for (int jj = 0; jj < SUB; ++jj) {
            int s = b0 + jj;
            float bx = B[3 * s], by = B[3 * s + 1], bz = B[3 * s + 2];
            float w = fmaf(bz, bz, fmaf(by, by, bx * bx));
            float v = fmaf(ax, bx, fmaf(ay, by, fmaf(az, bz, w)));
            int cand = (v == bestf) ? s : 0x7fffffff;
            idx = (cand < idx) ? cand : idx;
        }
        if (idx == 0x7fffffff) idx = b0;
        float d = An[3 * o] * Bn[3 * idx] + An[3 * o + 1] * Bn[3 * idx + 1]
                + An[3 * o + 2] * Bn[3 * idx + 2];
        c = (1.0f - d) * inv;
    }
#pragma unroll
    for (int off = 32; off > 0; off >>= 1) c += __shfl_down(c, off, 64);
    if (threadIdx.x == 0) atomicAdd(out, c);
}

extern "C" void kernel_launch(void* const* d_in, const int* in_sizes, int n_in,
                              void* d_out, int out_size, void* d_ws, size_t ws_size,
                              hipStream_t stream) {
    const float* p  = (const float*)d_in[0];   // [N,3] predicted points
    const float* pn = (const float*)d_in[1];   // [N,3] predicted normals (unit)
    const float* g  = (const float*)d_in[2];   // [M,3] gt points
    const float* gn = (const float*)d_in[3];   // [M,3] gt normals (unit)
    const int N = in_sizes[0] / 3;             // 8192
    const int M = in_sizes[2] / 3;             // 32768
    float* out = (float*)d_out;

    const int rowChunks = N / OWNERS;          // 8
    const int colChunks = M / OWNERS;          // 32
    const int rowGroups = M / CPB;             // 64
    const int colGroups = N / CPB;             // 16
    const int nChunks = rowChunks + colChunks; // 40

    // ws layout: mins[N+M] | ctr[nChunks] | done[1] | csum[nChunks]
    const size_t minsBytes = (size_t)(N + M) * sizeof(ull);
    const size_t initBytes = minsBytes + (size_t)(nChunks + 1) * sizeof(u32);
    const size_t needBytes = initBytes + (size_t)nChunks * sizeof(float);

    const bool geomOK = (N % OWNERS) == 0 && (M % OWNERS) == 0 &&
                        (N % CPB) == 0 && (M % CPB) == 0 &&
                        rowGroups >= 2 && colGroups >= 2 && nChunks >= 2;

    if (geomOK && ws_size >= needBytes) {
        // -------- primary: 2 dispatches (330 KB memset + fused kernel) --------
        ull* mins = (ull*)d_ws;
        u32* ctr  = (u32*)((char*)d_ws + minsBytes);
        u32* done = ctr + nChunks;
        float* csum = (float*)(done + 1);
        hipMemsetAsync(d_ws, 0xFF, initBytes, stream);  // mins=max, counters=-1
        const int blocks = rowChunks * rowGroups + colChunks * colGroups;  // 1024
        nn_fused<<<blocks, BLK, 0, stream>>>(
            p, g, pn, gn, mins, ctr, done, csum, out, N, M);
    } else {
        // -------- legacy r5-verified 3-dispatch path --------
        ull* rowmin = (ull*)d_ws;
        ull* colmin = rowmin + N;
        hipMemsetAsync(d_ws, 0xFF, (size_t)(N + M) * sizeof(ull), stream);
        const int rowSlices = M / L_SLICE;
        const int colSlices = N / L_SLICE;
        const int rowBlocks = (N / L_OWNERS) * rowSlices;
        const int colBlocks = (M / L_OWNERS) * colSlices;
        nn_min_dual<<<rowBlocks + colBlocks, BLK, 0, stream>>>(
            p, g, rowmin, colmin, out, rowBlocks, rowSlices, colSlices);
        const int tot = N + M;
        finalize_kernel<<<(tot + FBLK - 1) / FBLK, FBLK, 0, stream>>>(
            rowmin, colmin, p, g, pn, gn, out, N, M, 1.0f / N, 1.0f / M);
    }
}

// Round 7
// 120.744 us; speedup vs baseline: 1.7000x; 1.7000x over previous
//
#include <hip/hip_runtime.h>
#include <stdint.h>
#include <float.h>

#define BLK 256
#define IPT 8                   // owner points per thread (8 independent min-chains)
#define OWNERS (BLK * IPT)      // 2048 owners per block / per chunk
#define SLICE 256               // candidates staged per LDS fill (4 KB SoA)
#define SUB 64                  // subtile granularity for deferred-index recovery
#define KROW 64                 // candidate groups per row-side owner (cpb = M/64 = 512)
#define KCOL 32                 // candidate groups per col-side owner (cpb = N/32 = 256)
#define FBLK 64                 // finalize block = 1 wave -> 640 blocks

typedef unsigned long long ull;
typedef float v2f __attribute__((ext_vector_type(2)));

__device__ __forceinline__ v2f fma2(v2f a, v2f b, v2f c) {
    return __builtin_elementwise_fma(a, b, c);   // -> v_pk_fma_f32 (IEEE fma/half)
}

// Monotone float -> uint transform (preserves <, total order) and inverse.
__device__ __forceinline__ unsigned int ford(float f) {
    int b = __float_as_int(f);
    return (b >= 0) ? ((unsigned)b ^ 0x80000000u) : ~(unsigned)b;
}
__device__ __forceinline__ float ford_inv(unsigned int u) {
    int b = (u & 0x80000000u) ? (int)(u ^ 0x80000000u) : (int)~u;
    return __int_as_float(b);
}

// Phase 1 — ZERO atomics, ZERO memset (r7 test of the atomic-RMW-cap theory):
// each block owns a unique (owner-chunk, candidate-group) pair and writes its
// per-owner partial min to a PRIVATE slot ws[kgrp][owner] with a plain
// coalesced store (wave = 512 B contiguous). Every slot is written -> no init.
// Inner loop is r5's verified pk_fma chain (bit-exact recovery preserved).
// Slot order k ascending == candidate-base ascending, so the u64 min over
// slots in finalize reproduces the exact first-occurrence tie rule.
__global__ __launch_bounds__(BLK) void nn_scan(
    const float* __restrict__ p, const float* __restrict__ g,
    ull* __restrict__ wsR, ull* __restrict__ wsC,
    float* __restrict__ out, int N, int M)
{
    __shared__ float sbx[SLICE], sby[SLICE], sbz[SLICE], sbw[SLICE];

    if (blockIdx.x == 0 && threadIdx.x == 0) *out = 0.0f;  // fold memset(d_out)

    const int rowChunks = N / OWNERS;              // 4
    const int rowBlocks = rowChunks * KROW;        // 256

    const float* A; const float* B; ull* ws; int id, nK, NO, cpb;
    if ((int)blockIdx.x < rowBlocks) {
        id = blockIdx.x;             A = p; B = g; ws = wsR; nK = KROW; NO = N; cpb = M / KROW;
    } else {
        id = blockIdx.x - rowBlocks; A = g; B = p; ws = wsC; nK = KCOL; NO = M; cpb = N / KCOL;
    }
    const int chunk = id / nK;
    const int kgrp  = id - chunk * nK;
    const int c0 = kgrp * cpb;
    const int nStages = cpb / SLICE;               // row: 2, col: 1

    // ---- owner prologue (registers persist across stages) ----
    const int o0 = chunk * OWNERS + threadIdx.x;
    v2f ax2[IPT], ay2[IPT], az2[IPT];
    float best[IPT];
    int base[IPT];
#pragma unroll
    for (int r = 0; r < IPT; ++r) {
        int o = o0 + r * BLK;
        float axv = -2.0f * A[3 * o];
        float ayv = -2.0f * A[3 * o + 1];
        float azv = -2.0f * A[3 * o + 2];
        ax2[r] = (v2f){axv, axv};
        ay2[r] = (v2f){ayv, ayv};
        az2[r] = (v2f){azv, azv};
        best[r] = FLT_MAX;
        base[r] = c0;
    }

    for (int stage = 0; stage < nStages; ++stage) {
        const int gs0 = c0 + stage * SLICE;
        if (stage) __syncthreads();        // readers of previous stage done

        // Stage slice SoA (coords + |B|^2). Explicit fmaf: finalize recomputes
        // the identical expression so bit-exact equality holds.
        {
            int s = gs0 + threadIdx.x;     // SLICE == BLK: one candidate/thread
            float bx = B[3 * s], by = B[3 * s + 1], bz = B[3 * s + 2];
            float w = fmaf(bz, bz, fmaf(by, by, bx * bx));
            sbx[threadIdx.x] = bx; sby[threadIdx.x] = by;
            sbz[threadIdx.x] = bz; sbw[threadIdx.x] = w;
        }
        __syncthreads();

        for (int st = 0; st < SLICE; st += SUB) {
            float prev[IPT];
#pragma unroll
            for (int r = 0; r < IPT; ++r) prev[r] = best[r];
#pragma unroll 2
            for (int k = st; k < st + SUB; k += 2) {
                v2f qx = *(const v2f*)&sbx[k];   // k even -> 8B aligned broadcast
                v2f qy = *(const v2f*)&sby[k];
                v2f qz = *(const v2f*)&sbz[k];
                v2f qw = *(const v2f*)&sbw[k];
#pragma unroll
                for (int r = 0; r < IPT; ++r) {
                    v2f t = fma2(az2[r], qz, qw);     // 3 pk_fma = 2 candidates
                    t = fma2(ay2[r], qy, t);
                    t = fma2(ax2[r], qx, t);
                    best[r] = fminf(fminf(t.x, t.y), best[r]);   // -> v_min3_f32
                }
            }
#pragma unroll
            for (int r = 0; r < IPT; ++r)
                if (best[r] < prev[r]) base[r] = gs0 + st;  // strict <: first wins
        }
    }

    // ---- plain coalesced store to this block's private slot row ----
    ull* dst = ws + (size_t)kgrp * NO;     // ws[kgrp][owner]
#pragma unroll
    for (int r = 0; r < IPT; ++r)
        dst[o0 + r * BLK] = ((ull)ford(best[r]) << 32) | (unsigned)base[r];
}

// Phase 2: thread-per-owner. K-way u64 min over the owner's slots (each loop
// iteration is a fully-coalesced wave read: ws[k][o..o+63] = 512 B contiguous),
// then the verified branchless bit-exact 64-pt rescan + normal dot; one
// atomicAdd per wave.
__global__ __launch_bounds__(FBLK) void nn_reduce(
    const ull* __restrict__ wsR, const ull* __restrict__ wsC,
    const float* __restrict__ p, const float* __restrict__ g,
    const float* __restrict__ pn, const float* __restrict__ gn,
    float* __restrict__ out, int N, int M, float invN, float invM)
{
    int t = blockIdx.x * FBLK + threadIdx.x;
    float c = 0.0f;
    if (t < N + M) {
        const float* A; const float* B; const float* An; const float* Bn;
        const ull* ws; int o, K, NO; float inv;
        if (t < N) { o = t;     A = p; B = g; An = pn; Bn = gn; ws = wsR; K = KROW; NO = N; inv = invN; }
        else       { o = t - N; A = g; B = p; An = gn; Bn = pn; ws = wsC; K = KCOL; NO = M; inv = invM; }

        ull bestp = ws[o];                       // slot k=0
#pragma unroll 4
        for (int k = 1; k < K; ++k) {            // coalesced across lanes
            ull v2 = ws[(size_t)k * NO + o];
            bestp = (v2 < bestp) ? v2 : bestp;   // equal ford -> smaller base = first
        }

        float ax = -2.0f * A[3 * o];
        float ay = -2.0f * A[3 * o + 1];
        float az = -2.0f * A[3 * o + 2];
        float bestf = ford_inv((unsigned int)(bestp >> 32));
        int b0 = (int)(bestp & 0xffffffffull);

        // Branchless bit-exact first-match rescan (verified absmax=0 path).
        int idx = 0x7fffffff;
#pragma unroll 4
        for (int jj = 0; jj < SUB; ++jj) {
            int s = b0 + jj;
            float bx = B[3 * s], by = B[3 * s + 1], bz = B[3 * s + 2];
            float w = fmaf(bz, bz, fmaf(by, by, bx * bx));
            float v = fmaf(ax, bx, fmaf(ay, by, fmaf(az, bz, w)));
            int cand = (v == bestf) ? s : 0x7fffffff;
            idx = (cand < idx) ? cand : idx;     // ascending -> first match = min s
        }
        if (idx == 0x7fffffff) idx = b0;         // defensive; cannot trigger

        float d = An[3 * o] * Bn[3 * idx] + An[3 * o + 1] * Bn[3 * idx + 1]
                + An[3 * o + 2] * Bn[3 * idx + 2];
        c = (1.0f - d) * inv;
    }
#pragma unroll
    for (int off = 32; off > 0; off >>= 1) c += __shfl_down(c, off, 64);
    if (threadIdx.x == 0) atomicAdd(out, c);
}

// ======================= legacy fallback (r5-verified 3-dispatch path) =======================
#define L_SLICE 128

__global__ __launch_bounds__(BLK) void nn_min_dual(
    const float* __restrict__ p, const float* __restrict__ g,
    ull* __restrict__ rowmin, ull* __restrict__ colmin,
    float* __restrict__ out, int rowBlocks, int rowSlices, int colSlices)
{
    __shared__ float sbx[L_SLICE], sby[L_SLICE], sbz[L_SLICE], sbw[L_SLICE];
    if (blockIdx.x == 0 && threadIdx.x == 0) *out = 0.0f;
    const float* A; const float* B; ull* outmin; int id, nSlices;
    if ((int)blockIdx.x < rowBlocks) {
        id = blockIdx.x;             A = p; B = g; outmin = rowmin; nSlices = rowSlices;
    } else {
        id = blockIdx.x - rowBlocks; A = g; B = p; outmin = colmin; nSlices = colSlices;
    }
    const int chunk = id / nSlices;
    const int slice = id - chunk * nSlices;
    const int s0 = slice * L_SLICE;
    if (threadIdx.x < L_SLICE) {
        int s = s0 + threadIdx.x;
        float bx = B[3 * s], by = B[3 * s + 1], bz = B[3 * s + 2];
        float w = fmaf(bz, bz, fmaf(by, by, bx * bx));
        sbx[threadIdx.x] = bx; sby[threadIdx.x] = by;
        sbz[threadIdx.x] = bz; sbw[threadIdx.x] = w;
    }
    const int o0 = chunk * OWNERS + threadIdx.x;
    v2f ax2[IPT], ay2[IPT], az2[IPT];
    float best[IPT]; int base[IPT];
#pragma unroll
    for (int r = 0; r < IPT; ++r) {
        int o = o0 + r * BLK;
        float axv = -2.0f * A[3 * o], ayv = -2.0f * A[3 * o + 1], azv = -2.0f * A[3 * o + 2];
        ax2[r] = (v2f){axv, axv}; ay2[r] = (v2f){ayv, ayv}; az2[r] = (v2f){azv, azv};
        best[r] = FLT_MAX; base[r] = s0;
    }
    __syncthreads();
    for (int st = 0; st < L_SLICE; st += SUB) {
        float prev[IPT];
#pragma unroll
        for (int r = 0; r < IPT; ++r) prev[r] = best[r];
#pragma unroll 2
        for (int k = st; k < st + SUB; k += 2) {
            v2f qx = *(const v2f*)&sbx[k]; v2f qy = *(const v2f*)&sby[k];
            v2f qz = *(const v2f*)&sbz[k]; v2f qw = *(const v2f*)&sbw[k];
#pragma unroll
            for (int r = 0; r < IPT; ++r) {
                v2f t = fma2(az2[r], qz, qw);
                t = fma2(ay2[r], qy, t);
                t = fma2(ax2[r], qx, t);
                best[r] = fminf(fminf(t.x, t.y), best[r]);
            }
        }
#pragma unroll
        for (int r = 0; r < IPT; ++r)
            if (best[r] < prev[r]) base[r] = s0 + st;
    }
#pragma unroll
    for (int r = 0; r < IPT; ++r) {
        ull packed = ((ull)ford(best[r]) << 32) | (unsigned)base[r];
        atomicMin(&outmin[o0 + r * BLK], packed);
    }
}

__global__ __launch_bounds__(FBLK) void finalize_legacy(
    const ull* __restrict__ rowmin, const ull* __restrict__ colmin,
    const float* __restrict__ p, const float* __restrict__ g,
    const float* __restrict__ pn, const float* __restrict__ gn,
    float* __restrict__ out, int N, int M, float invN, float invM)
{
    int t = blockIdx.x * FBLK + threadIdx.x;
    float c = 0.0f;
    if (t < N + M) {
        const float* A; const float* B; const float* An; const float* Bn;
        ull packed; int o; float inv;
        if (t < N) { o = t;     A = p; B = g; An = pn; Bn = gn; packed = rowmin[o]; inv = invN; }
        else       { o = t - N; A = g; B = p; An = gn; Bn = pn; packed = colmin[o]; inv = invM; }
        float ax = -2.0f * A[3 * o], ay = -2.0f * A[3 * o + 1], az = -2.0f * A[3 * o + 2];
        float bestf = ford_inv((unsigned int)(packed >> 32));
        int b0 = (int)(packed & 0xffffffffull);
        int idx = 0x7fffffff;
#pragma unroll 4
        for (int jj = 0; jj < SUB; ++jj) {
            int s = b0 + jj;
            float bx = B[3 * s], by = B[3 * s + 1], bz = B[3 * s + 2];
            float w = fmaf(bz, bz, fmaf(by, by, bx * bx));
            float v = fmaf(ax, bx, fmaf(ay, by, fmaf(az, bz, w)));
            int cand = (v == bestf) ? s : 0x7fffffff;
            idx = (cand < idx) ? cand : idx;
        }
        if (idx == 0x7fffffff) idx = b0;
        float d = An[3 * o] * Bn[3 * idx] + An[3 * o + 1] * Bn[3 * idx + 1]
                + An[3 * o + 2] * Bn[3 * idx + 2];
        c = (1.0f - d) * inv;
    }
#pragma unroll
    for (int off = 32; off > 0; off >>= 1) c += __shfl_down(c, off, 64);
    if (threadIdx.x == 0) atomicAdd(out, c);
}

extern "C" void kernel_launch(void* const* d_in, const int* in_sizes, int n_in,
                              void* d_out, int out_size, void* d_ws, size_t ws_size,
                              hipStream_t stream) {
    const float* p  = (const float*)d_in[0];   // [N,3] predicted points
    const float* pn = (const float*)d_in[1];   // [N,3] predicted normals (unit)
    const float* g  = (const float*)d_in[2];   // [M,3] gt points
    const float* gn = (const float*)d_in[3];   // [M,3] gt normals (unit)
    const int N = in_sizes[0] / 3;             // 8192
    const int M = in_sizes[2] / 3;             // 32768
    float* out = (float*)d_out;

    // ws layout (primary): wsR[KROW][N] | wsC[KCOL][M]  = 4.2 + 8.4 = 12.6 MB
    const size_t wsRn = (size_t)KROW * N;
    const size_t wsCn = (size_t)KCOL * M;
    const size_t needBytes = (wsRn + wsCn) * sizeof(ull);

    const bool geomOK = (N % OWNERS) == 0 && (M % OWNERS) == 0 &&
                        (M % (KROW * SLICE)) == 0 && (N % (KCOL * SLICE)) == 0 &&
                        ((N + M) % FBLK) == 0 && (N % FBLK) == 0;

    if (geomOK && ws_size >= needBytes) {
        // -------- primary: 2 dispatches, no memsets, no atomics in phase 1 --------
        ull* wsR = (ull*)d_ws;
        ull* wsC = wsR + wsRn;
        const int blocks = (N / OWNERS) * KROW + (M / OWNERS) * KCOL;   // 768
        nn_scan<<<blocks, BLK, 0, stream>>>(p, g, wsR, wsC, out, N, M);
        nn_reduce<<<(N + M) / FBLK, FBLK, 0, stream>>>(
            wsR, wsC, p, g, pn, gn, out, N, M, 1.0f / N, 1.0f / M);
    } else {
        // -------- legacy r5-verified 3-dispatch path --------
        ull* rowmin = (ull*)d_ws;
        ull* colmin = rowmin + N;
        hipMemsetAsync(d_ws, 0xFF, (size_t)(N + M) * sizeof(ull), stream);
        const int rowSlices = M / L_SLICE;
        const int colSlices = N / L_SLICE;
        const int rowBlocks = (N / OWNERS) * rowSlices;
        const int colBlocks = (M / OWNERS) * colSlices;
        nn_min_dual<<<rowBlocks + colBlocks, BLK, 0, stream>>>(
            p, g, rowmin, colmin, out, rowBlocks, rowSlices, colSlices);
        finalize_legacy<<<(N + M + FBLK - 1) / FBLK, FBLK, 0, stream>>>(
            rowmin, colmin, p, g, pn, gn, out, N, M, 1.0f / N, 1.0f / M);
    }
}